// Round 3
// baseline (8739.066 us; speedup 1.0000x reference)
//
#include <hip/hip_runtime.h>
#include <stdint.h>

typedef unsigned short u16;
typedef unsigned int   u32;
typedef __attribute__((ext_vector_type(8))) short bf8v;          // 8 x bf16 MFMA frag (4 VGPR)
typedef __attribute__((ext_vector_type(4))) float f4v;           // MFMA acc frag
typedef __attribute__((ext_vector_type(8))) unsigned short us8v; // 16B bf16 vector

__device__ __forceinline__ float bfs(u16 u){ union { u32 i; float f; } v; v.i = ((u32)u) << 16; return v.f; }
__device__ __forceinline__ u16 f2bf(float f){ union { float f; u32 i; } v; v.f = f; u32 i = v.i; return (u16)((i + 0x7fffu + ((i >> 16) & 1u)) >> 16); }
__device__ __forceinline__ float sigm(float x){ return 1.f / (1.f + __expf(-x)); }
__device__ __forceinline__ float tanh_(float x){ float e = __expf(2.f * x); return 1.f - 2.f / (e + 1.f); }
// dtype-flagged input load: flag!=0 -> input stored as f32; else bf16(u16)
__device__ __forceinline__ float ldin(const void* p, size_t i, bool f32){
  return f32 ? ((const float*)p)[i] : bfs(((const u16*)p)[i]);
}

// ---------------- dtype detection ----------------
// Sample even u16 indices of feature_map. bf16 data: exponent field sane (~100%).
// f32 data: even u16 = low mantissa half -> uniform exponent field (~18% sane).
__global__ __launch_bounds__(256) void k_detect(const u16* __restrict__ p, int* __restrict__ flag){
  __shared__ int cnt;
  if (threadIdx.x == 0) cnt = 0;
  __syncthreads();
  int sane = 0;
  for (int i = threadIdx.x; i < 2048; i += 256){
    u16 v = p[2 * i];
    int e = (v >> 7) & 0xff;
    if (e >= 96 && e <= 140) sane++;
  }
  atomicAdd(&cnt, sane);
  __syncthreads();
  if (threadIdx.x == 0) *flag = (cnt < 1024) ? 1 : 0;   // 1 => f32 inputs/outputs
}

// ---------------- one-time / chunked prep ----------------

// feature_map (b,ci,hw) -> chunk (b_local,hw,ci) bf16, for 64 batches at b_base
__global__ __launch_bounds__(256) void k_transpose_fm(const void* __restrict__ fm, u16* __restrict__ out,
                                                      int b_base, const int* __restrict__ dtf){
  const bool f32in = (*dtf != 0);
  __shared__ u16 tile[64][65];
  int b = blockIdx.z, hw0 = blockIdx.x * 64, ci0 = blockIdx.y * 64;
  int tid = threadIdx.x;
  int hwl = tid & 63, ci_l = tid >> 6;
  #pragma unroll
  for (int r = 0; r < 16; ++r){
    int ci = ci_l * 16 + r;
    size_t idx = ((size_t)((b_base + b) * 512 + ci0 + ci)) * 256 + hw0 + hwl;
    tile[ci][hwl] = f32in ? f2bf(((const float*)fm)[idx]) : ((const u16*)fm)[idx];
  }
  __syncthreads();
  int cil = tid & 63, hw_l = tid >> 6;
  #pragma unroll
  for (int r = 0; r < 16; ++r){
    int hw = hw_l * 16 + r;
    out[((size_t)(b * 256 + hw0 + hw)) * 512 + ci0 + cil] = tile[cil][hw];
  }
}

// conv_m2h_w (co,ci,3,3) -> Wt (dydx,co,ci) bf16
__global__ __launch_bounds__(256) void k_wt_prep(const void* __restrict__ w, u16* __restrict__ wt,
                                                 const int* __restrict__ dtf){
  const bool f32in = (*dtf != 0);
  int idx = blockIdx.x * 256 + threadIdx.x;         // 9*512*512
  int ci = idx & 511, co = (idx >> 9) & 511, dydx = idx >> 18;
  size_t src = ((size_t)(co * 512 + ci)) * 9 + dydx;
  wt[idx] = f32in ? f2bf(((const float*)w)[src]) : ((const u16*)w)[src];
}

// ---------------- conv3x3 as implicit GEMM (MFMA bf16) ----------------
// Per launch: 64 batches. M=(b_local,y,x)=16384, N=co=512, K=9*512. Tile 128x128, BK=32.
__global__ __launch_bounds__(256) void k_conv(
    const u16* __restrict__ in_t,    // (64,256,512) b_local,hw,ci  bf16
    const u16* __restrict__ Wt,      // (9,512,512)  dydx,co,ci     bf16
    const void* __restrict__ cbias,
    u16* __restrict__ fmh, int b_base, const int* __restrict__ dtf)
{
  const bool f32in = (*dtf != 0);
  __shared__ u16 As[128 * 32];
  __shared__ u16 Bs[128 * 32];
  int tid = threadIdx.x;
  int wave = tid >> 6, lane = tid & 63;
  int nb = blockIdx.x & 3, mb = blockIdx.x >> 2;   // mb in [0,128)
  int m0 = mb * 128, n0 = nb * 128;
  int bb = m0 >> 8;                                 // local batch [0,64)
  int r = tid >> 1;
  int seg = (tid & 1) * 16;
  int hwl = (mb & 1) * 128 + r;
  int y = hwl >> 5, x = hwl & 31;
  const u16* aBase = in_t + ((size_t)bb * 256) * 512 + seg;
  const u16* bBase = Wt + ((size_t)(n0 + r)) * 512 + seg;
  int lm = lane & 15, quad = lane >> 4;
  int wm = (wave & 1) * 64, wn = (wave >> 1) * 64;
  f4v acc[4][4];
  #pragma unroll
  for (int i = 0; i < 4; ++i)
    #pragma unroll
    for (int j = 0; j < 4; ++j)
      acc[i][j] = (f4v){0.f, 0.f, 0.f, 0.f};

  for (int dydx = 0; dydx < 9; ++dydx){
    int dy = dydx / 3, dx = dydx - dy * 3;
    int yy = y + dy - 1, xx = x + dx - 1;
    bool ok = (yy >= 0) && (yy < 8) && (xx >= 0) && (xx < 32);
    const u16* aRow = aBase + (ptrdiff_t)(yy * 32 + xx) * 512;
    const u16* bRow = bBase + (size_t)dydx * 262144;
    for (int kc = 0; kc < 16; ++kc){
      us8v a0 = (us8v){0,0,0,0,0,0,0,0}, a1 = a0;
      if (ok){
        a0 = *(const us8v*)(aRow + kc * 32);
        a1 = *(const us8v*)(aRow + kc * 32 + 8);
      }
      us8v b0 = *(const us8v*)(bRow + kc * 32);
      us8v b1 = *(const us8v*)(bRow + kc * 32 + 8);
      __syncthreads();
      *(us8v*)&As[r * 32 + seg]     = a0;
      *(us8v*)&As[r * 32 + seg + 8] = a1;
      *(us8v*)&Bs[r * 32 + seg]     = b0;
      *(us8v*)&Bs[r * 32 + seg + 8] = b1;
      __syncthreads();
      bf8v af[4], bfr[4];
      #pragma unroll
      for (int i = 0; i < 4; ++i) af[i]  = *(const bf8v*)&As[(wm + i * 16 + lm) * 32 + quad * 8];
      #pragma unroll
      for (int j = 0; j < 4; ++j) bfr[j] = *(const bf8v*)&Bs[(wn + j * 16 + lm) * 32 + quad * 8];
      #pragma unroll
      for (int i = 0; i < 4; ++i)
        #pragma unroll
        for (int j = 0; j < 4; ++j)
          acc[i][j] = __builtin_amdgcn_mfma_f32_16x16x32_bf16(af[i], bfr[j], acc[i][j], 0, 0, 0);
    }
  }
  // C/D: col(co)=lane&15, row(m)=quad*4+reg -> 4 consecutive hw per lane
  #pragma unroll
  for (int j = 0; j < 4; ++j){
    int co = n0 + wn + j * 16 + lm;
    float bv = ldin(cbias, co, f32in);
    #pragma unroll
    for (int i = 0; i < 4; ++i){
      int mrow = m0 + wm + i * 16 + quad * 4;
      int hw = mrow & 255;
      ushort4 pk;
      pk.x = f2bf(acc[i][j][0] + bv);
      pk.y = f2bf(acc[i][j][1] + bv);
      pk.z = f2bf(acc[i][j][2] + bv);
      pk.w = f2bf(acc[i][j][3] + bv);
      *(ushort4*)&fmh[((size_t)((b_base + bb) * 512 + co)) * 256 + hw] = pk;
    }
  }
}

// ---------------- small dense ops ----------------

__global__ __launch_bounds__(256) void k_meanH(const void* __restrict__ H, float* __restrict__ outm,
                                               const int* __restrict__ dtf){
  const bool f32in = (*dtf != 0);
  int idx = blockIdx.x * 256 + threadIdx.x;  // 256*512
  int b = idx >> 9, k = idx & 511;
  float s = 0.f;
  #pragma unroll
  for (int t = 0; t < 26; ++t) s += ldin(H, ((size_t)(b * 26 + t)) * 512 + k, f32in);
  outm[idx] = s * (1.f / 26.f);
}

__global__ __launch_bounds__(256) void k_init(const void* __restrict__ hh, const void* __restrict__ hc,
                                              float* h1, float* c1, float* h2, float* c2,
                                              const int* __restrict__ dtf){
  const bool f32in = (*dtf != 0);
  int idx = blockIdx.x * 256 + threadIdx.x;  // 131072
  float h0 = 0.5f * (ldin(hh, idx, f32in) + ldin(hh, idx + 131072, f32in));
  float c0 = 0.5f * (ldin(hc, idx, f32in) + ldin(hc, idx + 131072, f32in));
  h1[idx] = h0; h2[idx] = h0; c1[idx] = c0; c2[idx] = c0;
}

// out[M=256,N] = A1@W1^T (+A2@W2^T) (+b1+b2) (+C0) (+onehot gather col of W1)
// A fp32 lda=512; W = raw input (bf16 or f32 per flag), row-major [N][ldw]; K per pass = 512.
__global__ __launch_bounds__(256) void k_gemm(
    const float* __restrict__ A1, const void* __restrict__ W1, int ldw1,
    const float* __restrict__ A2, const void* __restrict__ W2,
    const void* __restrict__ b1, const void* __restrict__ b2,
    const float* __restrict__ C0,
    const int* __restrict__ txt, int t, int ohbase,
    float* __restrict__ out, int N, const int* __restrict__ dtf)
{
  const bool f32in = (*dtf != 0);
  __shared__ float As[32][33];
  __shared__ float Ws[64][33];
  int tid = threadIdx.x;
  int n0 = blockIdx.x * 64, m0 = blockIdx.y * 32;
  float acc[2][4] = {{0.f,0.f,0.f,0.f},{0.f,0.f,0.f,0.f}};
  int ml = (tid >> 4) * 2, nl = (tid & 15) * 4;
  int sm = tid >> 3, sk = (tid & 7) * 4;
  int wn = tid >> 2, wk = (tid & 3) * 8;
  for (int pass = 0; pass < 2; ++pass){
    const float* A; const void* W; int ldw;
    if (pass == 0){ A = A1; W = W1; ldw = ldw1; }
    else { if (!A2) break; A = A2; W = W2; ldw = 512; }
    for (int k0 = 0; k0 < 512; k0 += 32){
      __syncthreads();
      float4 av = *(const float4*)&A[(size_t)(m0 + sm) * 512 + k0 + sk];
      As[sm][sk] = av.x; As[sm][sk+1] = av.y; As[sm][sk+2] = av.z; As[sm][sk+3] = av.w;
      size_t wbase = (size_t)(n0 + wn) * ldw + k0 + wk;
      if (f32in){
        const float* wp = (const float*)W + wbase;
        #pragma unroll
        for (int u2 = 0; u2 < 8; ++u2) Ws[wn][wk + u2] = wp[u2];
      } else {
        const u16* wp = (const u16*)W + wbase;
        #pragma unroll
        for (int u2 = 0; u2 < 4; ++u2){
          u32 pr = *(const u32*)(wp + u2 * 2);
          Ws[wn][wk + u2*2]     = __uint_as_float(pr << 16);
          Ws[wn][wk + u2*2 + 1] = __uint_as_float(pr & 0xffff0000u);
        }
      }
      __syncthreads();
      #pragma unroll
      for (int k = 0; k < 32; ++k){
        float a0 = As[ml][k], a1 = As[ml+1][k];
        float w0 = Ws[nl][k], w1 = Ws[nl+1][k], w2 = Ws[nl+2][k], w3 = Ws[nl+3][k];
        acc[0][0] = fmaf(a0,w0,acc[0][0]); acc[0][1] = fmaf(a0,w1,acc[0][1]);
        acc[0][2] = fmaf(a0,w2,acc[0][2]); acc[0][3] = fmaf(a0,w3,acc[0][3]);
        acc[1][0] = fmaf(a1,w0,acc[1][0]); acc[1][1] = fmaf(a1,w1,acc[1][1]);
        acc[1][2] = fmaf(a1,w2,acc[1][2]); acc[1][3] = fmaf(a1,w3,acc[1][3]);
      }
    }
  }
  #pragma unroll
  for (int i = 0; i < 2; ++i){
    int m = m0 + ml + i;
    int tv = txt ? txt[m * 26 + t] : 0;
    #pragma unroll
    for (int j = 0; j < 4; ++j){
      int n = n0 + nl + j;
      float v = acc[i][j];
      if (b1) v += ldin(b1, n, f32in);
      if (b2) v += ldin(b2, n, f32in);
      if (C0) v += C0[(size_t)m * N + n];
      if (txt) v += ldin(W1, (size_t)n * ldw1 + ohbase + tv, f32in);
      out[(size_t)m * N + n] = v;
    }
  }
}

// fused attention: e -> softmax -> context ; one block per batch
__global__ __launch_bounds__(256) void k_attn(const u16* __restrict__ fmh,
    const float* __restrict__ q, const void* __restrict__ sw, const void* __restrict__ sb,
    float* __restrict__ ctx, const int* __restrict__ dtf)
{
  const bool f32in = (*dtf != 0);
  __shared__ float qs[512], wss[512], sA[256], sR[256];
  int b = blockIdx.x, tid = threadIdx.x;
  qs[tid] = q[b * 512 + tid]; qs[tid + 256] = q[b * 512 + 256 + tid];
  wss[tid] = ldin(sw, tid, f32in); wss[tid + 256] = ldin(sw, tid + 256, f32in);
  __syncthreads();
  const u16* fb = fmh + (size_t)b * 512 * 256;
  float e0 = 0.f, e1 = 0.f, e2 = 0.f, e3 = 0.f;
  for (int c = 0; c < 512; c += 4){
    e0 = fmaf(tanh_(bfs(fb[(c+0)*256 + tid]) + qs[c+0]), wss[c+0], e0);
    e1 = fmaf(tanh_(bfs(fb[(c+1)*256 + tid]) + qs[c+1]), wss[c+1], e1);
    e2 = fmaf(tanh_(bfs(fb[(c+2)*256 + tid]) + qs[c+2]), wss[c+2], e2);
    e3 = fmaf(tanh_(bfs(fb[(c+3)*256 + tid]) + qs[c+3]), wss[c+3], e3);
  }
  float e = (e0 + e1) + (e2 + e3) + ldin(sb, 0, f32in);
  sR[tid] = e; __syncthreads();
  #pragma unroll
  for (int off = 128; off > 0; off >>= 1){
    if (tid < off) sR[tid] = fmaxf(sR[tid], sR[tid + off]);
    __syncthreads();
  }
  float mx = sR[0]; __syncthreads();
  float ex = __expf(e - mx);
  sR[tid] = ex; __syncthreads();
  #pragma unroll
  for (int off = 128; off > 0; off >>= 1){
    if (tid < off) sR[tid] += sR[tid + off];
    __syncthreads();
  }
  float inv = 1.f / sR[0];
  sA[tid] = ex * inv; __syncthreads();
  #pragma unroll
  for (int cc = 0; cc < 2; ++cc){
    int c = tid + cc * 256;
    const u16* row = fb + (size_t)c * 256;
    float s0 = 0.f, s1 = 0.f;
    for (int h8 = 0; h8 < 32; h8 += 2){
      us8v va = *(const us8v*)(row + h8 * 8);
      us8v vb = *(const us8v*)(row + h8 * 8 + 8);
      #pragma unroll
      for (int u2 = 0; u2 < 8; ++u2){
        s0 = fmaf(sA[h8*8 + u2],     bfs(va[u2]), s0);
        s1 = fmaf(sA[h8*8 + 8 + u2], bfs(vb[u2]), s1);
      }
    }
    ctx[(size_t)b * 512 + c] = s0 + s1;
  }
}

__global__ __launch_bounds__(256) void k_lstm(const float* __restrict__ g,
    const float* __restrict__ cp, float* __restrict__ hn, float* __restrict__ cn,
    u16* __restrict__ hidout, int t)
{
  int idx = blockIdx.x * 256 + threadIdx.x;  // 131072
  int b = idx >> 9, j = idx & 511;
  const float* gb = g + (size_t)b * 2048;
  float iv = sigm(gb[j]);
  float fv = sigm(gb[512 + j]);
  float gv = tanh_(gb[1024 + j]);
  float ov = sigm(gb[1536 + j]);
  float c = fv * cp[idx] + iv * gv;
  float h = ov * tanh_(c);
  cn[idx] = c; hn[idx] = h;
  if (hidout) hidout[((size_t)(b * 26 + t)) * 512 + j] = f2bf(h);
}

__global__ __launch_bounds__(256) void k_gen(const u16* __restrict__ hid,
    const void* __restrict__ gw, const void* __restrict__ gb, void* __restrict__ out,
    const int* __restrict__ dtf)
{
  const bool f32io = (*dtf != 0);
  int b = blockIdx.x, tid = threadIdx.x;
  for (int idx = tid; idx < 26 * 38; idx += 256){
    int t = idx / 38, cls = idx - t * 38;
    const u16* h = hid + ((size_t)(b * 26 + t)) * 512;
    float s0 = ldin(gb, cls, f32io), s1 = 0.f, s2 = 0.f, s3 = 0.f;
    for (int k = 0; k < 512; k += 4){
      s0 = fmaf(bfs(h[k]),   ldin(gw, (size_t)cls * 512 + k,   f32io), s0);
      s1 = fmaf(bfs(h[k+1]), ldin(gw, (size_t)cls * 512 + k+1, f32io), s1);
      s2 = fmaf(bfs(h[k+2]), ldin(gw, (size_t)cls * 512 + k+2, f32io), s2);
      s3 = fmaf(bfs(h[k+3]), ldin(gw, (size_t)cls * 512 + k+3, f32io), s3);
    }
    float v = (s0 + s1) + (s2 + s3);
    size_t o = ((size_t)(b * 26 + t)) * 38 + cls;
    if (f32io) ((float*)out)[o] = v;
    else       ((u16*)out)[o] = f2bf(v);
  }
}

extern "C" void kernel_launch(void* const* d_in, const int* in_sizes, int n_in,
                              void* d_out, int out_size, void* d_ws, size_t ws_size,
                              hipStream_t stream)
{
  (void)in_sizes; (void)n_in; (void)out_size; (void)ws_size;
  const void* fm      = d_in[0];
  const void* batchH  = d_in[1];
  const void* hh      = d_in[2];
  const void* hc      = d_in[3];
  const int*  text    = (const int*)d_in[4];
  const void* i2h_w   = d_in[5];
  const void* h2h_w   = d_in[6];
  const void* h2h_b   = d_in[7];
  const void* cm2h_w  = d_in[8];
  const void* cm2h_b  = d_in[9];
  const void* ch2h_w  = d_in[10];
  const void* ch2h_b  = d_in[11];
  const void* score_w = d_in[12];
  const void* score_b = d_in[13];
  const void* r1_wih  = d_in[14];
  const void* r1_whh  = d_in[15];
  const void* r1_bih  = d_in[16];
  const void* r1_bhh  = d_in[17];
  const void* hlin_w  = d_in[18];
  const void* hlin_b  = d_in[19];
  const void* r2_wih  = d_in[20];
  const void* r2_whh  = d_in[21];
  const void* r2_bih  = d_in[22];
  const void* r2_bhh  = d_in[23];
  const void* gen_w   = d_in[24];
  const void* gen_b   = d_in[25];

  // ---- workspace layout (total 88,604,928 B) ----
  char* ws = (char*)d_ws;
  u16* fmh   = (u16*)(ws + 0);              // 67,108,864 B (b,co,hw) bf16, live whole run
  u16* Wt    = (u16*)(ws + 67108864);       //  4,718,592 B (dydx,co,ci)
  char* S    = ws + 71827456;               // scratch region, 16,777,216 B
  u16* chunk = (u16*)S;                     // (64,256,512) bf16 — dead after conv rounds
  float* bh_mean = (float*)(S + 0);         // fp32 smalls overlay chunk (used after conv)
  float* bh_proj = (float*)(S + 524288);
  float* h1b[2] = { (float*)(S + 1048576), (float*)(S + 1572864) };
  float* c1b[2] = { (float*)(S + 2097152), (float*)(S + 2621440) };
  float* h2b[2] = { (float*)(S + 3145728), (float*)(S + 3670016) };
  float* c2b[2] = { (float*)(S + 4194304), (float*)(S + 4718592) };
  float* vbuf   = (float*)(S + 5242880);
  float* qbuf   = (float*)(S + 5767168);
  float* ctx    = (float*)(S + 6291456);
  float* cur    = (float*)(S + 6815744);
  float* gbuf   = (float*)(S + 7340032);    // 2,097,152 B — shared by both LSTMs
  u16*   hid    = (u16*)(S + 9437184);      // 6,815,744 B (b,t,hs) bf16
  int*   dtf    = (int*)(ws + 88604672);    // dtype flag

  k_detect<<<1, 256, 0, stream>>>((const u16*)fm, dtf);
  k_wt_prep<<<9216, 256, 0, stream>>>(cm2h_w, Wt, dtf);
  for (int rb = 0; rb < 4; ++rb){
    k_transpose_fm<<<dim3(4, 8, 64), 256, 0, stream>>>(fm, chunk, rb * 64, dtf);
    k_conv<<<512, 256, 0, stream>>>(chunk, Wt, cm2h_b, fmh, rb * 64, dtf);
  }
  k_meanH<<<512, 256, 0, stream>>>(batchH, bh_mean, dtf);
  k_gemm<<<dim3(8, 8), 256, 0, stream>>>(bh_mean, i2h_w, 512, nullptr, nullptr,
      nullptr, nullptr, nullptr, nullptr, 0, 0, bh_proj, 512, dtf);
  k_init<<<512, 256, 0, stream>>>(hh, hc, h1b[0], c1b[0], h2b[0], c2b[0], dtf);

  for (int t = 0; t < 26; ++t){
    int r = t & 1, w = r ^ 1;
    // v = bh_proj + h2@h2h_w^T + h2h_b
    k_gemm<<<dim3(8, 8), 256, 0, stream>>>(h2b[r], h2h_w, 512, nullptr, nullptr,
        h2h_b, nullptr, bh_proj, nullptr, 0, 0, vbuf, 512, dtf);
    // q = v@w1x1^T + conv_h2h_b
    k_gemm<<<dim3(8, 8), 256, 0, stream>>>(vbuf, ch2h_w, 512, nullptr, nullptr,
        ch2h_b, nullptr, nullptr, nullptr, 0, 0, qbuf, 512, dtf);
    k_attn<<<256, 256, 0, stream>>>(fmh, qbuf, score_w, score_b, ctx, dtf);
    // gates1 = [ctx|onehot]@r1_wih^T + h1@r1_whh^T + b_ih + b_hh
    k_gemm<<<dim3(32, 8), 256, 0, stream>>>(ctx, r1_wih, 550, h1b[r], r1_whh,
        r1_bih, r1_bhh, nullptr, text, t, 512, gbuf, 2048, dtf);
    k_lstm<<<512, 256, 0, stream>>>(gbuf, c1b[r], h1b[w], c1b[w], nullptr, 0);
    // cur = h1n@hlin_w^T + hlin_b
    k_gemm<<<dim3(8, 8), 256, 0, stream>>>(h1b[w], hlin_w, 512, nullptr, nullptr,
        hlin_b, nullptr, nullptr, nullptr, 0, 0, cur, 512, dtf);
    // gates2 = cur@r2_wih^T + h2@r2_whh^T + b_ih + b_hh
    k_gemm<<<dim3(32, 8), 256, 0, stream>>>(cur, r2_wih, 512, h2b[r], r2_whh,
        r2_bih, r2_bhh, nullptr, nullptr, 0, 0, gbuf, 2048, dtf);
    k_lstm<<<512, 256, 0, stream>>>(gbuf, c2b[r], h2b[w], c2b[w], hid, t);
  }
  k_gen<<<256, 256, 0, stream>>>(hid, gen_w, gen_b, d_out, dtf);
}

// Round 4
// 6151.037 us; speedup vs baseline: 1.4207x; 1.4207x over previous
//
#include <hip/hip_runtime.h>
#include <stdint.h>

typedef unsigned short u16;
typedef unsigned int   u32;
typedef __attribute__((ext_vector_type(8))) short bf8v;          // 8 x bf16 MFMA frag (4 VGPR)
typedef __attribute__((ext_vector_type(4))) float f4v;           // MFMA acc frag
typedef __attribute__((ext_vector_type(8))) unsigned short us8v; // 16B bf16 vector

__device__ __forceinline__ float bfs(u16 u){ union { u32 i; float f; } v; v.i = ((u32)u) << 16; return v.f; }
__device__ __forceinline__ u16 f2bf(float f){ union { float f; u32 i; } v; v.f = f; u32 i = v.i; return (u16)((i + 0x7fffu + ((i >> 16) & 1u)) >> 16); }
__device__ __forceinline__ float sigm(float x){ return 1.f / (1.f + __expf(-x)); }
__device__ __forceinline__ float tanh_(float x){ float e = __expf(2.f * x); return 1.f - 2.f / (e + 1.f); }

// ---------------- one-time / chunked prep ----------------

// feature_map f32 (b,ci,hw) -> chunk bf16 (b_local,hw,ci), 64 batches at b_base
__global__ __launch_bounds__(256) void k_transpose_fm(const float* __restrict__ fm, u16* __restrict__ out, int b_base){
  __shared__ u16 tile[64][65];
  int b = blockIdx.z, hw0 = blockIdx.x * 64, ci0 = blockIdx.y * 64;
  int tid = threadIdx.x;
  int hwl = tid & 63, ci_l = tid >> 6;
  #pragma unroll
  for (int r = 0; r < 16; ++r){
    int ci = ci_l * 16 + r;
    tile[ci][hwl] = f2bf(fm[((size_t)((b_base + b) * 512 + ci0 + ci)) * 256 + hw0 + hwl]);
  }
  __syncthreads();
  int cil = tid & 63, hw_l = tid >> 6;
  #pragma unroll
  for (int r = 0; r < 16; ++r){
    int hw = hw_l * 16 + r;
    out[((size_t)(b * 256 + hw0 + hw)) * 512 + ci0 + cil] = tile[cil][hw];
  }
}

// conv_m2h_w f32 (co,ci,3,3) -> Wt bf16 (dydx,co,ci)
__global__ __launch_bounds__(256) void k_wt_prep(const float* __restrict__ w, u16* __restrict__ wt){
  int idx = blockIdx.x * 256 + threadIdx.x;         // 9*512*512
  int ci = idx & 511, co = (idx >> 9) & 511, dydx = idx >> 18;
  wt[idx] = f2bf(w[((size_t)(co * 512 + ci)) * 9 + dydx]);
}

// generic f32 -> bf16 convert (k-contiguous row-major weights)
__global__ __launch_bounds__(256) void k_cvt(const float* __restrict__ src, u16* __restrict__ dst, int n){
  int idx = blockIdx.x * 256 + threadIdx.x;
  if (idx < n) dst[idx] = f2bf(src[idx]);
}
// r1_wih (2048 x 550) -> first 512 cols, bf16 [2048][512]
__global__ __launch_bounds__(256) void k_cvt_rw1(const float* __restrict__ src, u16* __restrict__ dst){
  int idx = blockIdx.x * 256 + threadIdx.x;   // 2048*512
  int n = idx >> 9, k = idx & 511;
  dst[idx] = f2bf(src[(size_t)n * 550 + k]);
}
// gen_w (38 x 512) -> bf16 [48][512] zero-padded
__global__ __launch_bounds__(256) void k_cvt_gen(const float* __restrict__ src, u16* __restrict__ dst){
  int idx = blockIdx.x * 256 + threadIdx.x;   // 48*512
  int n = idx >> 9, k = idx & 511;
  dst[idx] = (n < 38) ? f2bf(src[(size_t)n * 512 + k]) : (u16)0;
}

// ---------------- conv3x3 as implicit GEMM (MFMA bf16) ----------------
// Per launch: 64 batches. M=16384, N=512, K=9*512. Tile 128x128, BK=32.
__global__ __launch_bounds__(256) void k_conv(
    const u16* __restrict__ in_t, const u16* __restrict__ Wt,
    const float* __restrict__ cbias, u16* __restrict__ fmh, int b_base)
{
  __shared__ u16 As[128 * 32];
  __shared__ u16 Bs[128 * 32];
  int tid = threadIdx.x;
  int wave = tid >> 6, lane = tid & 63;
  int nb = blockIdx.x & 3, mb = blockIdx.x >> 2;
  int m0 = mb * 128, n0 = nb * 128;
  int bb = m0 >> 8;
  int r = tid >> 1;
  int seg = (tid & 1) * 16;
  int hwl = (mb & 1) * 128 + r;
  int y = hwl >> 5, x = hwl & 31;
  const u16* aBase = in_t + ((size_t)bb * 256) * 512 + seg;
  const u16* bBase = Wt + ((size_t)(n0 + r)) * 512 + seg;
  int lm = lane & 15, quad = lane >> 4;
  int wm = (wave & 1) * 64, wn = (wave >> 1) * 64;
  f4v acc[4][4];
  #pragma unroll
  for (int i = 0; i < 4; ++i)
    #pragma unroll
    for (int j = 0; j < 4; ++j)
      acc[i][j] = (f4v){0.f, 0.f, 0.f, 0.f};

  for (int dydx = 0; dydx < 9; ++dydx){
    int dy = dydx / 3, dx = dydx - dy * 3;
    int yy = y + dy - 1, xx = x + dx - 1;
    bool ok = (yy >= 0) && (yy < 8) && (xx >= 0) && (xx < 32);
    const u16* aRow = aBase + (ptrdiff_t)(yy * 32 + xx) * 512;
    const u16* bRow = bBase + (size_t)dydx * 262144;
    for (int kc = 0; kc < 16; ++kc){
      us8v a0 = (us8v){0,0,0,0,0,0,0,0}, a1 = a0;
      if (ok){
        a0 = *(const us8v*)(aRow + kc * 32);
        a1 = *(const us8v*)(aRow + kc * 32 + 8);
      }
      us8v b0 = *(const us8v*)(bRow + kc * 32);
      us8v b1 = *(const us8v*)(bRow + kc * 32 + 8);
      __syncthreads();
      *(us8v*)&As[r * 32 + seg]     = a0;
      *(us8v*)&As[r * 32 + seg + 8] = a1;
      *(us8v*)&Bs[r * 32 + seg]     = b0;
      *(us8v*)&Bs[r * 32 + seg + 8] = b1;
      __syncthreads();
      bf8v af[4], bfr[4];
      #pragma unroll
      for (int i = 0; i < 4; ++i) af[i]  = *(const bf8v*)&As[(wm + i * 16 + lm) * 32 + quad * 8];
      #pragma unroll
      for (int j = 0; j < 4; ++j) bfr[j] = *(const bf8v*)&Bs[(wn + j * 16 + lm) * 32 + quad * 8];
      #pragma unroll
      for (int i = 0; i < 4; ++i)
        #pragma unroll
        for (int j = 0; j < 4; ++j)
          acc[i][j] = __builtin_amdgcn_mfma_f32_16x16x32_bf16(af[i], bfr[j], acc[i][j], 0, 0, 0);
    }
  }
  #pragma unroll
  for (int j = 0; j < 4; ++j){
    int co = n0 + wn + j * 16 + lm;
    float bv = cbias[co];
    #pragma unroll
    for (int i = 0; i < 4; ++i){
      int mrow = m0 + wm + i * 16 + quad * 4;
      int hw = mrow & 255;
      ushort4 pk;
      pk.x = f2bf(acc[i][j][0] + bv);
      pk.y = f2bf(acc[i][j][1] + bv);
      pk.z = f2bf(acc[i][j][2] + bv);
      pk.w = f2bf(acc[i][j][3] + bv);
      *(ushort4*)&fmh[((size_t)((b_base + bb) * 512 + co)) * 256 + hw] = pk;
    }
  }
}

// ---------------- MFMA recurrence GEMM ----------------
// OUT[M][N] = A1@W1^T (+A2@W2^T) + b1 + b2 + C0 + onehot(Woh col 512+txt)
// A*, W* bf16 k-contig (lda/ldw=512, K=512 per pass). grid(N/128, M/128), 256 thr.
__global__ __launch_bounds__(256) void k_mgemm(
    const u16* __restrict__ A1, const u16* __restrict__ W1,
    const u16* __restrict__ A2, const u16* __restrict__ W2,
    const float* __restrict__ b1, const float* __restrict__ b2,
    const float* __restrict__ C0,
    const float* __restrict__ Woh, const int* __restrict__ txt, int t,
    void* __restrict__ out, int obf16, int N)
{
  __shared__ u16 As[128 * 32];
  __shared__ u16 Bs[128 * 32];
  int tid = threadIdx.x;
  int wave = tid >> 6, lane = tid & 63;
  int m0 = blockIdx.y * 128, n0 = blockIdx.x * 128;
  int r = tid >> 1, seg = (tid & 1) * 16;
  int lm = lane & 15, quad = lane >> 4;
  int wm = (wave & 1) * 64, wn = (wave >> 1) * 64;
  f4v acc[4][4];
  #pragma unroll
  for (int i = 0; i < 4; ++i)
    #pragma unroll
    for (int j = 0; j < 4; ++j)
      acc[i][j] = (f4v){0.f, 0.f, 0.f, 0.f};

  for (int pass = 0; pass < 2; ++pass){
    const u16* A = pass ? A2 : A1;
    const u16* W = pass ? W2 : W1;
    if (!A) break;
    const u16* aRow = A + (size_t)(m0 + r) * 512 + seg;
    const u16* bRow = W + (size_t)(n0 + r) * 512 + seg;
    for (int kc = 0; kc < 16; ++kc){
      us8v a0 = *(const us8v*)(aRow + kc * 32);
      us8v a1 = *(const us8v*)(aRow + kc * 32 + 8);
      us8v b0 = *(const us8v*)(bRow + kc * 32);
      us8v b1 = *(const us8v*)(bRow + kc * 32 + 8);
      __syncthreads();
      *(us8v*)&As[r * 32 + seg]     = a0;
      *(us8v*)&As[r * 32 + seg + 8] = a1;
      *(us8v*)&Bs[r * 32 + seg]     = b0;
      *(us8v*)&Bs[r * 32 + seg + 8] = b1;
      __syncthreads();
      bf8v af[4], bfr[4];
      #pragma unroll
      for (int i = 0; i < 4; ++i) af[i]  = *(const bf8v*)&As[(wm + i * 16 + lm) * 32 + quad * 8];
      #pragma unroll
      for (int j = 0; j < 4; ++j) bfr[j] = *(const bf8v*)&Bs[(wn + j * 16 + lm) * 32 + quad * 8];
      #pragma unroll
      for (int i = 0; i < 4; ++i)
        #pragma unroll
        for (int j = 0; j < 4; ++j)
          acc[i][j] = __builtin_amdgcn_mfma_f32_16x16x32_bf16(af[i], bfr[j], acc[i][j], 0, 0, 0);
    }
  }
  // epilogue: m = m0+wm+i*16+quad*4+reg (batch row), n = n0+wn+j*16+lm
  #pragma unroll
  for (int j = 0; j < 4; ++j){
    int n = n0 + wn + j * 16 + lm;
    float badd = 0.f;
    if (b1) badd += b1[n];
    if (b2) badd += b2[n];
    #pragma unroll
    for (int i = 0; i < 4; ++i){
      int mb = m0 + wm + i * 16 + quad * 4;
      #pragma unroll
      for (int reg = 0; reg < 4; ++reg){
        int m = mb + reg;
        float v = acc[i][j][reg] + badd;
        if (C0) v += C0[(size_t)m * N + n];
        if (Woh) v += Woh[(size_t)n * 550 + 512 + txt[m * 26 + t]];
        if (obf16) ((u16*)out)[(size_t)m * N + n] = f2bf(v);
        else       ((float*)out)[(size_t)m * N + n] = v;
      }
    }
  }
}

// ---------------- small dense ops ----------------

__global__ __launch_bounds__(256) void k_meanH(const float* __restrict__ H, float* __restrict__ outm){
  int idx = blockIdx.x * 256 + threadIdx.x;  // 256*512
  int b = idx >> 9, k = idx & 511;
  float s = 0.f;
  #pragma unroll
  for (int t = 0; t < 26; ++t) s += H[((size_t)(b * 26 + t)) * 512 + k];
  outm[idx] = s * (1.f / 26.f);
}

// one-off f32 VALU GEMM: bh_proj[256][512] = bh_mean @ i2h_w^T (raw f32 weights)
__global__ __launch_bounds__(256) void k_pgemm(const float* __restrict__ A, const float* __restrict__ W,
                                               float* __restrict__ out){
  __shared__ float As[32][33];
  __shared__ float Ws[64][33];
  int tid = threadIdx.x;
  int n0 = blockIdx.x * 64, m0 = blockIdx.y * 32;
  float acc[2][4] = {{0.f,0.f,0.f,0.f},{0.f,0.f,0.f,0.f}};
  int ml = (tid >> 4) * 2, nl = (tid & 15) * 4;
  int sm = tid >> 3, sk = (tid & 7) * 4;
  int wn = tid >> 2, wk = (tid & 3) * 8;
  for (int k0 = 0; k0 < 512; k0 += 32){
    __syncthreads();
    float4 av = *(const float4*)&A[(size_t)(m0 + sm) * 512 + k0 + sk];
    As[sm][sk] = av.x; As[sm][sk+1] = av.y; As[sm][sk+2] = av.z; As[sm][sk+3] = av.w;
    const float* wp = W + (size_t)(n0 + wn) * 512 + k0 + wk;
    #pragma unroll
    for (int u2 = 0; u2 < 8; ++u2) Ws[wn][wk + u2] = wp[u2];
    __syncthreads();
    #pragma unroll
    for (int k = 0; k < 32; ++k){
      float a0 = As[ml][k], a1 = As[ml+1][k];
      float w0 = Ws[nl][k], w1 = Ws[nl+1][k], w2 = Ws[nl+2][k], w3 = Ws[nl+3][k];
      acc[0][0] = fmaf(a0,w0,acc[0][0]); acc[0][1] = fmaf(a0,w1,acc[0][1]);
      acc[0][2] = fmaf(a0,w2,acc[0][2]); acc[0][3] = fmaf(a0,w3,acc[0][3]);
      acc[1][0] = fmaf(a1,w0,acc[1][0]); acc[1][1] = fmaf(a1,w1,acc[1][1]);
      acc[1][2] = fmaf(a1,w2,acc[1][2]); acc[1][3] = fmaf(a1,w3,acc[1][3]);
    }
  }
  #pragma unroll
  for (int i = 0; i < 2; ++i)
    #pragma unroll
    for (int j = 0; j < 4; ++j)
      out[(size_t)(m0 + ml + i) * 512 + n0 + nl + j] = acc[i][j];
}

__global__ __launch_bounds__(256) void k_init(const float* __restrict__ hh, const float* __restrict__ hc,
                                              u16* h1, float* c1, u16* h2, float* c2){
  int idx = blockIdx.x * 256 + threadIdx.x;  // 131072
  float h0 = 0.5f * (hh[idx] + hh[idx + 131072]);
  float c0 = 0.5f * (hc[idx] + hc[idx + 131072]);
  u16 hb = f2bf(h0);
  h1[idx] = hb; h2[idx] = hb; c1[idx] = c0; c2[idx] = c0;
}

// fused attention: e -> softmax -> context ; one block per batch. q bf16 in, ctx bf16 out.
__global__ __launch_bounds__(256) void k_attn(const u16* __restrict__ fmh,
    const u16* __restrict__ q, const float* __restrict__ sw, const float* __restrict__ sb,
    u16* __restrict__ ctx)
{
  __shared__ float qs[512], wss[512], sA[256], sR[256];
  int b = blockIdx.x, tid = threadIdx.x;
  qs[tid] = bfs(q[b * 512 + tid]); qs[tid + 256] = bfs(q[b * 512 + 256 + tid]);
  wss[tid] = sw[tid];              wss[tid + 256] = sw[tid + 256];
  __syncthreads();
  const u16* fb = fmh + (size_t)b * 512 * 256;
  float e0 = 0.f, e1 = 0.f, e2 = 0.f, e3 = 0.f;
  for (int c = 0; c < 512; c += 4){
    e0 = fmaf(tanh_(bfs(fb[(c+0)*256 + tid]) + qs[c+0]), wss[c+0], e0);
    e1 = fmaf(tanh_(bfs(fb[(c+1)*256 + tid]) + qs[c+1]), wss[c+1], e1);
    e2 = fmaf(tanh_(bfs(fb[(c+2)*256 + tid]) + qs[c+2]), wss[c+2], e2);
    e3 = fmaf(tanh_(bfs(fb[(c+3)*256 + tid]) + qs[c+3]), wss[c+3], e3);
  }
  float e = (e0 + e1) + (e2 + e3) + sb[0];
  sR[tid] = e; __syncthreads();
  #pragma unroll
  for (int off = 128; off > 0; off >>= 1){
    if (tid < off) sR[tid] = fmaxf(sR[tid], sR[tid + off]);
    __syncthreads();
  }
  float mx = sR[0]; __syncthreads();
  float ex = __expf(e - mx);
  sR[tid] = ex; __syncthreads();
  #pragma unroll
  for (int off = 128; off > 0; off >>= 1){
    if (tid < off) sR[tid] += sR[tid + off];
    __syncthreads();
  }
  float inv = 1.f / sR[0];
  sA[tid] = ex * inv; __syncthreads();
  #pragma unroll
  for (int cc = 0; cc < 2; ++cc){
    int c = tid + cc * 256;
    const u16* row = fb + (size_t)c * 256;
    float s0 = 0.f, s1 = 0.f;
    for (int h8 = 0; h8 < 32; h8 += 2){
      us8v va = *(const us8v*)(row + h8 * 8);
      us8v vb = *(const us8v*)(row + h8 * 8 + 8);
      #pragma unroll
      for (int u2 = 0; u2 < 8; ++u2){
        s0 = fmaf(sA[h8*8 + u2],     bfs(va[u2]), s0);
        s1 = fmaf(sA[h8*8 + 8 + u2], bfs(vb[u2]), s1);
      }
    }
    ctx[(size_t)b * 512 + c] = f2bf(s0 + s1);
  }
}

__global__ __launch_bounds__(256) void k_lstm(const float* __restrict__ g,
    const float* __restrict__ cp, u16* __restrict__ hn, float* __restrict__ cn,
    u16* __restrict__ hidout, int t)
{
  int idx = blockIdx.x * 256 + threadIdx.x;  // 131072
  int b = idx >> 9, j = idx & 511;
  const float* gb = g + (size_t)b * 2048;
  float iv = sigm(gb[j]);
  float fv = sigm(gb[512 + j]);
  float gv = tanh_(gb[1024 + j]);
  float ov = sigm(gb[1536 + j]);
  float c = fv * cp[idx] + iv * gv;
  float h = ov * tanh_(c);
  u16 hb = f2bf(h);
  cn[idx] = c; hn[idx] = hb;
  if (hidout) hidout[((size_t)(b * 26 + t)) * 512 + j] = hb;
}

// final projection: out[6656][38] = hid @ genw^T + gen_b. Tile 128x48, grid 52.
__global__ __launch_bounds__(256) void k_gen(const u16* __restrict__ hid,
    const u16* __restrict__ genw, const float* __restrict__ gb, float* __restrict__ out)
{
  __shared__ u16 As[128 * 32];
  __shared__ u16 Bs[48 * 32];
  int tid = threadIdx.x;
  int wave = tid >> 6, lane = tid & 63;
  int m0 = blockIdx.x * 128;
  int r = tid >> 1, seg = (tid & 1) * 16;
  int lm = lane & 15, quad = lane >> 4;
  int mw = wave * 32;
  f4v acc[2][3];
  #pragma unroll
  for (int i = 0; i < 2; ++i)
    #pragma unroll
    for (int j = 0; j < 3; ++j)
      acc[i][j] = (f4v){0.f, 0.f, 0.f, 0.f};
  const u16* aRow = hid + (size_t)(m0 + r) * 512 + seg;
  const u16* bRow = genw + (size_t)r * 512 + seg;   // valid only tid<96
  for (int kc = 0; kc < 16; ++kc){
    us8v a0 = *(const us8v*)(aRow + kc * 32);
    us8v a1 = *(const us8v*)(aRow + kc * 32 + 8);
    us8v b0, b1;
    if (tid < 96){
      b0 = *(const us8v*)(bRow + kc * 32);
      b1 = *(const us8v*)(bRow + kc * 32 + 8);
    }
    __syncthreads();
    *(us8v*)&As[r * 32 + seg]     = a0;
    *(us8v*)&As[r * 32 + seg + 8] = a1;
    if (tid < 96){
      *(us8v*)&Bs[r * 32 + seg]     = b0;
      *(us8v*)&Bs[r * 32 + seg + 8] = b1;
    }
    __syncthreads();
    bf8v af[2], bfr[3];
    #pragma unroll
    for (int i = 0; i < 2; ++i) af[i]  = *(const bf8v*)&As[(mw + i * 16 + lm) * 32 + quad * 8];
    #pragma unroll
    for (int j = 0; j < 3; ++j) bfr[j] = *(const bf8v*)&Bs[(j * 16 + lm) * 32 + quad * 8];
    #pragma unroll
    for (int i = 0; i < 2; ++i)
      #pragma unroll
      for (int j = 0; j < 3; ++j)
        acc[i][j] = __builtin_amdgcn_mfma_f32_16x16x32_bf16(af[i], bfr[j], acc[i][j], 0, 0, 0);
  }
  #pragma unroll
  for (int j = 0; j < 3; ++j){
    int n = j * 16 + lm;
    if (n >= 38) continue;
    float bv = gb[n];
    #pragma unroll
    for (int i = 0; i < 2; ++i){
      int mb = m0 + mw + i * 16 + quad * 4;
      #pragma unroll
      for (int reg = 0; reg < 4; ++reg)
        out[(size_t)(mb + reg) * 38 + n] = acc[i][j][reg] + bv;
    }
  }
}

extern "C" void kernel_launch(void* const* d_in, const int* in_sizes, int n_in,
                              void* d_out, int out_size, void* d_ws, size_t ws_size,
                              hipStream_t stream)
{
  (void)in_sizes; (void)n_in; (void)out_size; (void)ws_size;
  const float* fm      = (const float*)d_in[0];
  const float* batchH  = (const float*)d_in[1];
  const float* hh      = (const float*)d_in[2];
  const float* hc      = (const float*)d_in[3];
  const int*   text    = (const int*)d_in[4];
  const float* i2h_w   = (const float*)d_in[5];
  const float* h2h_w   = (const float*)d_in[6];
  const float* h2h_b   = (const float*)d_in[7];
  const float* cm2h_w  = (const float*)d_in[8];
  const float* cm2h_b  = (const float*)d_in[9];
  const float* ch2h_w  = (const float*)d_in[10];
  const float* ch2h_b  = (const float*)d_in[11];
  const float* score_w = (const float*)d_in[12];
  const float* score_b = (const float*)d_in[13];
  const float* r1_wih  = (const float*)d_in[14];
  const float* r1_whh  = (const float*)d_in[15];
  const float* r1_bih  = (const float*)d_in[16];
  const float* r1_bhh  = (const float*)d_in[17];
  const float* hlin_w  = (const float*)d_in[18];
  const float* hlin_b  = (const float*)d_in[19];
  const float* r2_wih  = (const float*)d_in[20];
  const float* r2_whh  = (const float*)d_in[21];
  const float* r2_bih  = (const float*)d_in[22];
  const float* r2_bhh  = (const float*)d_in[23];
  const float* gen_w   = (const float*)d_in[24];
  const float* gen_b   = (const float*)d_in[25];

  // ---- workspace (exact-fit 88,604,672 B; proven budget 88.6 MB) ----
  char* ws = (char*)d_ws;
  u16* fmh = (u16*)(ws + 0);                 // 67,108,864 B, live whole run
  char* R  = ws + 67108864;                  // 21,495,808 B dual-phase region
  // conv phase:
  u16* Wt    = (u16*)(R + 0);                // 4,718,592
  u16* chunk = (u16*)(R + 4718592);          // 16,777,216
  // post-conv phase (overlays Wt+chunk):
  u16* r1wB  = (u16*)(R + 0);                // 2,097,152  r1_wih[:, :512] bf16
  u16* r1hB  = (u16*)(R + 2097152);          // 2,097,152  r1_whh bf16
  u16* r2wB  = (u16*)(R + 4194304);          // 2,097,152  r2_wih bf16
  u16* r2hB  = (u16*)(R + 6291456);          // 2,097,152  r2_whh bf16
  u16* h2hB  = (u16*)(R + 8388608);          //   524,288  h2h_w bf16
  u16* ch2hB = (u16*)(R + 8912896);          //   524,288  conv_h2h 1x1 bf16
  u16* hlinB = (u16*)(R + 9437184);          //   524,288  hlin_w bf16
  u16* slotA = (u16*)(R + 9961472);          //   262,144  v / ctx / cur (bf16, disjoint lifetimes)
  u16* qb    = (u16*)(R + 10223616);         //   262,144  q bf16
  u16* h1    = (u16*)(R + 10485760);         //   262,144
  u16* h2    = (u16*)(R + 10747904);         //   262,144
  float* c1  = (float*)(R + 11010048);       //   524,288
  float* c2  = (float*)(R + 11534336);       //   524,288
  float* gbuf = (float*)(R + 12058624);      // 2,097,152  gates f32 (bh_mean + genw overlay)
  float* bh_mean = (float*)(R + 12058624);   //   524,288  (inside gbuf, prologue only)
  u16*  genw = (u16*)(R + 12058624);         //    49,152  (inside gbuf, epilogue only)
  float* bh_proj = (float*)(R + 14155776);   //   524,288
  u16*  hid  = (u16*)(R + 14680064);         // 6,815,744  (b,t,hs) bf16

  // ---- conv phase ----
  k_wt_prep<<<9216, 256, 0, stream>>>(cm2h_w, Wt);
  for (int rb = 0; rb < 4; ++rb){
    k_transpose_fm<<<dim3(4, 8, 64), 256, 0, stream>>>(fm, chunk, rb * 64);
    k_conv<<<512, 256, 0, stream>>>(chunk, Wt, cm2h_b, fmh, rb * 64);
  }
  // ---- weight converts (overwrite conv staging) ----
  k_cvt_rw1<<<4096, 256, 0, stream>>>(r1_wih, r1wB);
  k_cvt<<<4096, 256, 0, stream>>>(r1_whh, r1hB, 1048576);
  k_cvt<<<4096, 256, 0, stream>>>(r2_wih, r2wB, 1048576);
  k_cvt<<<4096, 256, 0, stream>>>(r2_whh, r2hB, 1048576);
  k_cvt<<<1024, 256, 0, stream>>>(h2h_w, h2hB, 262144);
  k_cvt<<<1024, 256, 0, stream>>>(ch2h_w, ch2hB, 262144);
  k_cvt<<<1024, 256, 0, stream>>>(hlin_w, hlinB, 262144);
  // ---- prologue ----
  k_meanH<<<512, 256, 0, stream>>>(batchH, bh_mean);
  k_pgemm<<<dim3(8, 8), 256, 0, stream>>>(bh_mean, i2h_w, bh_proj);
  k_init<<<512, 256, 0, stream>>>(hh, hc, h1, c1, h2, c2);

  // ---- 26-step recurrence ----
  for (int t = 0; t < 26; ++t){
    // v = bh_proj + h2@h2h^T + h2h_b  -> slotA (bf16)
    k_mgemm<<<dim3(4, 2), 256, 0, stream>>>(h2, h2hB, nullptr, nullptr,
        h2h_b, nullptr, bh_proj, nullptr, nullptr, 0, slotA, 1, 512);
    // q = v@w1x1^T + ch2h_b  -> qb (bf16)
    k_mgemm<<<dim3(4, 2), 256, 0, stream>>>(slotA, ch2hB, nullptr, nullptr,
        ch2h_b, nullptr, nullptr, nullptr, nullptr, 0, qb, 1, 512);
    // attention -> ctx in slotA (bf16)
    k_attn<<<256, 256, 0, stream>>>(fmh, qb, score_w, score_b, slotA);
    // gates1 = ctx@r1_wih[:512]^T + h1@r1_whh^T + b + onehot -> gbuf (f32)
    k_mgemm<<<dim3(16, 2), 256, 0, stream>>>(slotA, r1wB, h1, r1hB,
        r1_bih, r1_bhh, nullptr, r1_wih, text, t, gbuf, 0, 2048);
    k_lstm<<<512, 256, 0, stream>>>(gbuf, c1, h1, c1, nullptr, 0);
    // cur = h1@hlin^T + hlin_b -> slotA (bf16)
    k_mgemm<<<dim3(4, 2), 256, 0, stream>>>(h1, hlinB, nullptr, nullptr,
        hlin_b, nullptr, nullptr, nullptr, nullptr, 0, slotA, 1, 512);
    // gates2 = cur@r2_wih^T + h2@r2_whh^T + b -> gbuf (f32)
    k_mgemm<<<dim3(16, 2), 256, 0, stream>>>(slotA, r2wB, h2, r2hB,
        r2_bih, r2_bhh, nullptr, nullptr, nullptr, 0, gbuf, 0, 2048);
    k_lstm<<<512, 256, 0, stream>>>(gbuf, c2, h2, c2, hid, t);
  }
  // ---- final projection ----
  k_cvt_gen<<<96, 256, 0, stream>>>(gen_w, genw);
  k_gen<<<52, 256, 0, stream>>>(hid, genw, gen_b, (float*)d_out);
}